// Round 8
// baseline (191.580 us; speedup 1.0000x reference)
//
#include <hip/hip_runtime.h>
#include <hip/hip_cooperative_groups.h>
#include <cmath>

namespace cg = cooperative_groups;

constexpr int B_ = 2, H_ = 8, N_ = 2048, DK_ = 64, DV_ = 64;
constexpr int BH_ = B_ * H_;      // 16
constexpr int C_ = 64;            // chunk size
constexpr int NC_ = N_ / C_;      // 32 chunks per (b,h)
constexpr int NCH_ = BH_ * NC_;   // 512 chunks total

using f32x16 = __attribute__((ext_vector_type(16))) float;
using bf16x8 = __attribute__((ext_vector_type(8))) __bf16;

__device__ inline unsigned short bfr(float x) {
  unsigned u = __float_as_uint(x);
  return (unsigned short)((u + 0x7FFFu + ((u >> 16) & 1u)) >> 16);
}
__device__ inline unsigned pk2(float lo, float hi) {
  return (unsigned)bfr(lo) | ((unsigned)bfr(hi) << 16);
}
// swizzled ushort index into a [64][64] bf16 tile (row stride 128B)
__device__ inline int swi(int row, int a) {
  return (row * 128 + (((a * 2) ^ ((row & 7) << 4)))) >> 1;
}

// ---------------------------------------------------------------------------
// Kernel 1: per-row coefficients (round-1 proven shape — DO NOT TOUCH).
// ---------------------------------------------------------------------------
__global__ __launch_bounds__(256) void coef_kernel(const float* __restrict__ om,
                                                   float* __restrict__ qc,
                                                   float* __restrict__ kc) {
  int row = blockIdx.x * 4 + (threadIdx.x >> 6);
  int lane = threadIdx.x & 63;
  const float* r = om + (size_t)row * N_;
  float s = 0.f;
#pragma unroll
  for (int kk = 0; kk < N_ / 256; ++kk) {
    float4 v4 = *(const float4*)(r + kk * 256 + lane * 4);
    s += (v4.x + v4.y) + (v4.z + v4.w);
  }
#pragma unroll
  for (int off = 32; off > 0; off >>= 1) s += __shfl_xor(s, off, 64);
  if (lane == 0) {
    float o0 = r[0];
    qc[row] = o0 / sqrtf(s);
    kc[row] = 1.0f / o0;
  }
}

// ---------------------------------------------------------------------------
// Fused tail (cooperative, 512 x 256, 2 blocks/CU):
//  phase 1: stage q/k/v once; f32 chunk kv-sums; f32 in-chunk cumsum of kbar
//           (last row = chunk ksum).
//  grid.sync
//  phase 2: exclusive prefix scan over chunks (in-place, float4, prefetch-8)
//  grid.sync
//  phase 3: S = QbKbT (causal, bf16 MFMA), O = S*V + Qb*Dpre (bf16 MFMA),
//           P fully f32, out = O / max(|P|,1).
// ---------------------------------------------------------------------------
__global__ __launch_bounds__(256, 2) void fused_tail(
    const float* __restrict__ qg, const float* __restrict__ kg,
    const float* __restrict__ vg, const float* __restrict__ qc,
    const float* __restrict__ kc, float* __restrict__ lksum,
    float* __restrict__ lkv, float* __restrict__ outg) {
  __shared__ float Tc[2][64][68];          // f32 kbar / cumsum (ping-pong, +4 pad)
  __shared__ unsigned short qb[64 * 64];   // qbar bf16 swizzled
  __shared__ unsigned short kb[64 * 64];   // kbar bf16 swizzled
  __shared__ unsigned short vT[64 * 64];   // V^T bf16 swizzled
  __shared__ float poolv[64 * 64];         // phase1: f32 V; phase3: dT+sS bf16
  __shared__ float Tl[64];                 // T_pre (f32)
  __shared__ float Pf[64];                 // 1/P

  const int chunk = blockIdx.x;
  const int bh = chunk >> 5, ci = chunk & 31;
  const int r0 = ci * C_;
  const int rowb = bh * N_ + r0;
  const size_t gbase = (size_t)rowb * DK_;
  const int t = threadIdx.x;
  const int i = t >> 2, a0 = (t & 3) * 16;

  float xq[16];   // f32 qbar row-fragment, survives to phase 3

  // ---- phase 1: stage everything once ----
  {
    float qcv = qc[rowb + i];
    float kcv = kc[rowb + i];
    float xk[16], xv[16];
    {
      const float* qp = qg + gbase + (size_t)i * 64 + a0;
      const float* kp = kg + gbase + (size_t)i * 64 + a0;
      const float* vp = vg + gbase + (size_t)i * 64 + a0;
#pragma unroll
      for (int u = 0; u < 4; ++u) {
        *(float4*)&xq[u * 4] = *(const float4*)(qp + u * 4);
        *(float4*)&xk[u * 4] = *(const float4*)(kp + u * 4);
        *(float4*)&xv[u * 4] = *(const float4*)(vp + u * 4);
      }
    }
#pragma unroll
    for (int u = 0; u < 16; ++u) { xq[u] *= qcv; xk[u] *= kcv; }
#pragma unroll
    for (int u4 = 0; u4 < 4; ++u4) {
      *(float4*)&Tc[0][i][a0 + u4 * 4] = *(const float4*)&xk[u4 * 4];
      *(float4*)&poolv[i * 64 + a0 + u4 * 4] = *(const float4*)&xv[u4 * 4];
    }
    unsigned* qbu = (unsigned*)qb;
    unsigned* kbu = (unsigned*)kb;
#pragma unroll
    for (int u = 0; u < 8; ++u) {
      int a = a0 + 2 * u;
      int bi = (i * 128 + (((a * 2) ^ ((i & 7) << 4)))) >> 2;
      qbu[bi] = pk2(xq[2 * u], xq[2 * u + 1]);
      kbu[bi] = pk2(xk[2 * u], xk[2 * u + 1]);
    }
#pragma unroll
    for (int u = 0; u < 16; ++u) vT[swi(a0 + u, i)] = bfr(xv[u]);
  }
  __syncthreads();

  // ---- phase 1b: chunk kv-sums, f32 (reads Tc[0] seed + poolv) ----
  {
    int dk0 = (t & 15) * 4, dv0 = (t >> 4) * 4;
    float acc[4][4] = {};
    for (int r = 0; r < C_; ++r) {
      float4 k4 = *(const float4*)&Tc[0][r][dk0];
      float4 v4 = *(const float4*)&poolv[r * 64 + dv0];
      float ka[4] = {k4.x, k4.y, k4.z, k4.w};
      float va[4] = {v4.x, v4.y, v4.z, v4.w};
#pragma unroll
      for (int ii = 0; ii < 4; ++ii)
#pragma unroll
        for (int jj = 0; jj < 4; ++jj) acc[ii][jj] += ka[ii] * va[jj];
    }
    float* kvc = lkv + (size_t)chunk * (DK_ * DV_);
#pragma unroll
    for (int ii = 0; ii < 4; ++ii)
      *(float4*)(kvc + (size_t)(dk0 + ii) * DV_ + dv0) =
          make_float4(acc[ii][0], acc[ii][1], acc[ii][2], acc[ii][3]);
  }
  __syncthreads();

  // ---- phase 1c: f32 in-chunk inclusive cumsum (Hillis-Steele, 6 steps) ----
  {
    int p = 0;
#pragma unroll
    for (int step = 1; step < 64; step <<= 1) {
      float4 cur[4], prv[4];
#pragma unroll
      for (int u4 = 0; u4 < 4; ++u4) {
        cur[u4] = *(const float4*)&Tc[p][i][a0 + u4 * 4];
        if (i >= step)
          prv[u4] = *(const float4*)&Tc[p][i - step][a0 + u4 * 4];
        else
          prv[u4] = make_float4(0.f, 0.f, 0.f, 0.f);
      }
#pragma unroll
      for (int u4 = 0; u4 < 4; ++u4) {
        float4 w = make_float4(cur[u4].x + prv[u4].x, cur[u4].y + prv[u4].y,
                               cur[u4].z + prv[u4].z, cur[u4].w + prv[u4].w);
        *(float4*)&Tc[p ^ 1][i][a0 + u4 * 4] = w;
      }
      __syncthreads();
      p ^= 1;
    }
  }
  // chunk ksum = last cumsum row
  if (i == 63) {
#pragma unroll
    for (int u = 0; u < 16; ++u)
      lksum[(size_t)chunk * DK_ + a0 + u] = Tc[0][63][a0 + u];
  }

  cg::this_grid().sync();

  // ---- phase 2: exclusive prefix scan (float4, in-place, prefetch-8) ----
  {
    constexpr int PER4 = (DK_ * DV_) / 4 + DK_ / 4;   // 1040 per bh
    int tid = blockIdx.x * 256 + t;
    if (tid < BH_ * PER4) {
      int sbh = tid / PER4, e = tid - sbh * PER4;
      float4* p;
      size_t stride;
      if (e < (DK_ * DV_) / 4) {
        p = (float4*)(lkv + (size_t)sbh * NC_ * (DK_ * DV_)) + e;
        stride = (DK_ * DV_) / 4;
      } else {
        p = (float4*)(lksum + (size_t)sbh * NC_ * DK_) + (e - (DK_ * DV_) / 4);
        stride = DK_ / 4;
      }
      float4 run = make_float4(0.f, 0.f, 0.f, 0.f);
      float4 buf[8];
      for (int b = 0; b < NC_ / 8; ++b) {
#pragma unroll
        for (int u = 0; u < 8; ++u) buf[u] = p[(size_t)(b * 8 + u) * stride];
#pragma unroll
        for (int u = 0; u < 8; ++u) {
          p[(size_t)(b * 8 + u) * stride] = run;
          run.x += buf[u].x; run.y += buf[u].y;
          run.z += buf[u].z; run.w += buf[u].w;
        }
      }
    }
  }

  cg::this_grid().sync();

  // ---- phase 3: outputs ----
  unsigned short* dT = (unsigned short*)poolv;          // D^T bf16 swizzled
  unsigned short* sS = (unsigned short*)(poolv + 2048); // S bf16 swizzled
  {
    const float* dp = lkv + (size_t)chunk * (DK_ * DV_) + (size_t)i * 64 + a0;
    float xd[16];
#pragma unroll
    for (int u = 0; u < 4; ++u) *(float4*)&xd[u * 4] = *(const float4*)(dp + u * 4);
#pragma unroll
    for (int u = 0; u < 16; ++u) dT[swi(a0 + u, i)] = bfr(xd[u]);
    if (t < 64) Tl[t] = lksum[(size_t)chunk * DK_ + t];
  }
  __syncthreads();

  // P[i] = xq . (T_pre + Tc[i])  (all f32)
  {
    float part = 0.f;
#pragma unroll
    for (int u = 0; u < 16; ++u)
      part += xq[u] * (Tl[a0 + u] + Tc[0][i][a0 + u]);
    part += __shfl_xor(part, 1, 64);
    part += __shfl_xor(part, 2, 64);
    if ((t & 3) == 0) Pf[i] = 1.0f / fmaxf(fabsf(part), 1.0f);
  }

  const int lane = t & 63, w = t >> 6;
  const int wr = w >> 1, wc = w & 1;
  const int half = lane >> 5, col = lane & 31;
  const int arow = 32 * wr + col;
  const int bcol = 32 * wc + col;

  // M1: S = Qb KbT
  f32x16 accS;
#pragma unroll
  for (int r = 0; r < 16; ++r) accS[r] = 0.f;
#pragma unroll
  for (int kk = 0; kk < 4; ++kk) {
    int aa = kk * 16 + half * 8;
    bf16x8 af = *(const bf16x8*)&qb[swi(arow, aa)];
    bf16x8 bf = *(const bf16x8*)&kb[swi(bcol, aa)];
    accS = __builtin_amdgcn_mfma_f32_32x32x16_bf16(af, bf, accS, 0, 0, 0);
  }
#pragma unroll
  for (int r = 0; r < 16; ++r) {
    int iloc = (r & 3) + 8 * (r >> 2) + 4 * half;
    int ii = 32 * wr + iloc;
    int jj = 32 * wc + col;
    float m = (jj <= ii) ? accS[r] : 0.f;
    sS[swi(ii, jj)] = bfr(m);
  }
  __syncthreads();   // sS + Pf visible

  // M2+M3: O = S*V + Qb*D
  f32x16 acc;
#pragma unroll
  for (int r = 0; r < 16; ++r) acc[r] = 0.f;
#pragma unroll
  for (int kk = 0; kk < 4; ++kk) {
    int j0 = kk * 16 + half * 8;
    bf16x8 af = *(const bf16x8*)&sS[swi(arow, j0)];
    bf16x8 bf = *(const bf16x8*)&vT[swi(bcol, j0)];
    acc = __builtin_amdgcn_mfma_f32_32x32x16_bf16(af, bf, acc, 0, 0, 0);
  }
#pragma unroll
  for (int kk = 0; kk < 4; ++kk) {
    int aa = kk * 16 + half * 8;
    bf16x8 af = *(const bf16x8*)&qb[swi(arow, aa)];
    bf16x8 bf = *(const bf16x8*)&dT[swi(bcol, aa)];
    acc = __builtin_amdgcn_mfma_f32_32x32x16_bf16(af, bf, acc, 0, 0, 0);
  }

  float* ob = outg + (size_t)rowb * DV_;
#pragma unroll
  for (int r = 0; r < 16; ++r) {
    int iloc = (r & 3) + 8 * (r >> 2) + 4 * half;
    int ii = 32 * wr + iloc;
    int cc = 32 * wc + col;
    ob[(size_t)ii * DV_ + cc] = acc[r] * Pf[ii];
  }
}

// ===========================================================================
// Fallback path: round-7 proven kernels (used only if coop launch fails).
// ===========================================================================
__global__ __launch_bounds__(256) void chunksum_kernel(const float* __restrict__ kg,
                                                       const float* __restrict__ vg,
                                                       const float* __restrict__ kc,
                                                       float* __restrict__ ksum,
                                                       float* __restrict__ kvsum) {
  __shared__ float kbf[C_][DK_];
  __shared__ float vs[C_][DV_];
  int chunk = blockIdx.x;
  int bh = chunk / NC_, ci = chunk - bh * NC_;
  int r0 = ci * C_;
  size_t gbase = ((size_t)bh * N_ + r0) * DK_;
  int t = threadIdx.x;
#pragma unroll
  for (int p = 0; p < 4; ++p) {
    int f = t + p * 256;
    int row = f >> 4, col = (f & 15) * 4;
    float sc = kc[bh * N_ + r0 + row];
    float4 k4 = *(const float4*)(kg + gbase + (size_t)f * 4);
    k4.x *= sc; k4.y *= sc; k4.z *= sc; k4.w *= sc;
    *(float4*)&kbf[row][col] = k4;
    *(float4*)&vs[row][col] = *(const float4*)(vg + gbase + (size_t)f * 4);
  }
  __syncthreads();
  int dk0 = (t & 15) * 4, dv0 = (t >> 4) * 4;
  float acc[4][4] = {};
  float ks[4] = {};
  for (int r = 0; r < C_; ++r) {
    float4 k4 = *(const float4*)&kbf[r][dk0];
    float4 v4 = *(const float4*)&vs[r][dv0];
    float ka[4] = {k4.x, k4.y, k4.z, k4.w};
    float va[4] = {v4.x, v4.y, v4.z, v4.w};
#pragma unroll
    for (int ii = 0; ii < 4; ++ii) {
      ks[ii] += ka[ii];
#pragma unroll
      for (int jj = 0; jj < 4; ++jj) acc[ii][jj] += ka[ii] * va[jj];
    }
  }
  float* kvc = kvsum + (size_t)chunk * (DK_ * DV_);
#pragma unroll
  for (int ii = 0; ii < 4; ++ii)
    *(float4*)(kvc + (size_t)(dk0 + ii) * DV_ + dv0) =
        make_float4(acc[ii][0], acc[ii][1], acc[ii][2], acc[ii][3]);
  if (t < 16) {
#pragma unroll
    for (int ii = 0; ii < 4; ++ii) ksum[(size_t)chunk * DK_ + dk0 + ii] = ks[ii];
  }
}

__global__ __launch_bounds__(256) void scan_kernel(float* __restrict__ ksum,
                                                   float* __restrict__ kvsum) {
  constexpr int PER = DK_ * DV_ + DK_;
  int idx = blockIdx.x * 256 + threadIdx.x;
  if (idx >= BH_ * PER) return;
  int bh = idx / PER, e = idx - bh * PER;
  float run = 0.f;
  if (e < DK_ * DV_) {
    float* p = kvsum + (size_t)bh * NC_ * (DK_ * DV_) + e;
    for (int ci = 0; ci < NC_; ++ci) {
      float tv = p[(size_t)ci * (DK_ * DV_)];
      p[(size_t)ci * (DK_ * DV_)] = run;
      run += tv;
    }
  } else {
    float* p = ksum + (size_t)bh * NC_ * DK_ + (e - DK_ * DV_);
    for (int ci = 0; ci < NC_; ++ci) {
      float tv = p[(size_t)ci * DK_];
      p[(size_t)ci * DK_] = run;
      run += tv;
    }
  }
}

__global__ __launch_bounds__(256) void out_mfma_kernel(
    const float* __restrict__ qg, const float* __restrict__ kg,
    const float* __restrict__ vg, const float* __restrict__ qc,
    const float* __restrict__ kc, const float* __restrict__ ksum,
    const float* __restrict__ kvsum, float* __restrict__ outg) {
  __shared__ unsigned short qb[64 * 64];
  __shared__ unsigned short kb[64 * 64];
  __shared__ unsigned short sS[64 * 64];
  __shared__ unsigned short vT[64 * 64];
  __shared__ unsigned short dT[64 * 64];
  __shared__ float Tc[2][64][68];
  __shared__ float Tl[64];
  __shared__ float Pf[64];

  const int chunk = blockIdx.x;
  const int bh = chunk >> 5, ci = chunk & 31;
  const int r0 = ci * C_;
  const int rowb = bh * N_ + r0;
  const size_t gbase = (size_t)rowb * DK_;
  const int t = threadIdx.x;
  const int i = t >> 2, a0 = (t & 3) * 16;

  float xq[16];
  {
    float qcv = qc[rowb + i];
    float kcv = kc[rowb + i];
    float xk[16], xv[16], xd[16];
    {
      const float* qp = qg + gbase + (size_t)i * 64 + a0;
      const float* kp = kg + gbase + (size_t)i * 64 + a0;
      const float* vp = vg + gbase + (size_t)i * 64 + a0;
      const float* dp = kvsum + (size_t)chunk * (DK_ * DV_) + (size_t)i * 64 + a0;
#pragma unroll
      for (int u = 0; u < 4; ++u) {
        *(float4*)&xq[u * 4] = *(const float4*)(qp + u * 4);
        *(float4*)&xk[u * 4] = *(const float4*)(kp + u * 4);
        *(float4*)&xv[u * 4] = *(const float4*)(vp + u * 4);
        *(float4*)&xd[u * 4] = *(const float4*)(dp + u * 4);
      }
    }
#pragma unroll
    for (int u = 0; u < 16; ++u) { xq[u] *= qcv; xk[u] *= kcv; }
#pragma unroll
    for (int u4 = 0; u4 < 4; ++u4)
      *(float4*)&Tc[0][i][a0 + u4 * 4] = *(const float4*)&xk[u4 * 4];
    unsigned* qbu = (unsigned*)qb;
    unsigned* kbu = (unsigned*)kb;
#pragma unroll
    for (int u = 0; u < 8; ++u) {
      int a = a0 + 2 * u;
      int bi = (i * 128 + (((a * 2) ^ ((i & 7) << 4)))) >> 2;
      qbu[bi] = pk2(xq[2 * u], xq[2 * u + 1]);
      kbu[bi] = pk2(xk[2 * u], xk[2 * u + 1]);
    }
#pragma unroll
    for (int u = 0; u < 16; ++u) {
      int c = a0 + u;
      vT[swi(c, i)] = bfr(xv[u]);
      dT[swi(c, i)] = bfr(xd[u]);
    }
    if (t < 64) Tl[t] = ksum[(size_t)chunk * DK_ + t];
  }
  __syncthreads();
  {
    int p = 0;
#pragma unroll
    for (int step = 1; step < 64; step <<= 1) {
      float4 cur[4], prv[4];
#pragma unroll
      for (int u4 = 0; u4 < 4; ++u4) {
        cur[u4] = *(const float4*)&Tc[p][i][a0 + u4 * 4];
        if (i >= step)
          prv[u4] = *(const float4*)&Tc[p][i - step][a0 + u4 * 4];
        else
          prv[u4] = make_float4(0.f, 0.f, 0.f, 0.f);
      }
#pragma unroll
      for (int u4 = 0; u4 < 4; ++u4) {
        float4 w = make_float4(cur[u4].x + prv[u4].x, cur[u4].y + prv[u4].y,
                               cur[u4].z + prv[u4].z, cur[u4].w + prv[u4].w);
        *(float4*)&Tc[p ^ 1][i][a0 + u4 * 4] = w;
      }
      __syncthreads();
      p ^= 1;
    }
  }
  {
    float part = 0.f;
#pragma unroll
    for (int u = 0; u < 16; ++u)
      part += xq[u] * (Tl[a0 + u] + Tc[0][i][a0 + u]);
    part += __shfl_xor(part, 1, 64);
    part += __shfl_xor(part, 2, 64);
    if ((t & 3) == 0) Pf[i] = 1.0f / fmaxf(fabsf(part), 1.0f);
  }
  const int lane = t & 63, w = t >> 6;
  const int wr = w >> 1, wc = w & 1;
  const int half = lane >> 5, col = lane & 31;
  const int arow = 32 * wr + col;
  const int bcol = 32 * wc + col;
  f32x16 accS;
#pragma unroll
  for (int r = 0; r < 16; ++r) accS[r] = 0.f;
#pragma unroll
  for (int kk = 0; kk < 4; ++kk) {
    int aa = kk * 16 + half * 8;
    bf16x8 af = *(const bf16x8*)&qb[swi(arow, aa)];
    bf16x8 bf = *(const bf16x8*)&kb[swi(bcol, aa)];
    accS = __builtin_amdgcn_mfma_f32_32x32x16_bf16(af, bf, accS, 0, 0, 0);
  }
#pragma unroll
  for (int r = 0; r < 16; ++r) {
    int iloc = (r & 3) + 8 * (r >> 2) + 4 * half;
    int ii = 32 * wr + iloc;
    int jj = 32 * wc + col;
    float m = (jj <= ii) ? accS[r] : 0.f;
    sS[swi(ii, jj)] = bfr(m);
  }
  __syncthreads();
  f32x16 acc;
#pragma unroll
  for (int r = 0; r < 16; ++r) acc[r] = 0.f;
#pragma unroll
  for (int kk = 0; kk < 4; ++kk) {
    int j0 = kk * 16 + half * 8;
    bf16x8 af = *(const bf16x8*)&sS[swi(arow, j0)];
    bf16x8 bf = *(const bf16x8*)&vT[swi(bcol, j0)];
    acc = __builtin_amdgcn_mfma_f32_32x32x16_bf16(af, bf, acc, 0, 0, 0);
  }
#pragma unroll
  for (int kk = 0; kk < 4; ++kk) {
    int aa = kk * 16 + half * 8;
    bf16x8 af = *(const bf16x8*)&qb[swi(arow, aa)];
    bf16x8 bf = *(const bf16x8*)&dT[swi(bcol, aa)];
    acc = __builtin_amdgcn_mfma_f32_32x32x16_bf16(af, bf, acc, 0, 0, 0);
  }
  float* ob = outg + (size_t)rowb * DV_;
#pragma unroll
  for (int r = 0; r < 16; ++r) {
    int iloc = (r & 3) + 8 * (r >> 2) + 4 * half;
    int ii = 32 * wr + iloc;
    int cc = 32 * wc + col;
    ob[(size_t)ii * DV_ + cc] = acc[r] * Pf[ii];
  }
}

// ---------------------------------------------------------------------------
extern "C" void kernel_launch(void* const* d_in, const int* in_sizes, int n_in,
                              void* d_out, int out_size, void* d_ws, size_t ws_size,
                              hipStream_t stream) {
  const float* q = (const float*)d_in[0];
  const float* k = (const float*)d_in[1];
  const float* v = (const float*)d_in[2];
  const float* om = (const float*)d_in[3];
  float* out = (float*)d_out;

  float* ws = (float*)d_ws;
  float* qc = ws;                          // BH_*N_       = 32768
  float* kc = qc + BH_ * N_;               // BH_*N_       = 32768
  float* ksum = kc + BH_ * N_;             // NCH_*DK_     = 32768
  float* kv = ksum + (size_t)NCH_ * DK_;   // NCH_*DK_*DV_ = 2,097,152

  coef_kernel<<<BH_ * N_ / 4, 256, 0, stream>>>(om, qc, kc);

  void* args[] = {(void*)&q, (void*)&k, (void*)&v, (void*)&qc, (void*)&kc,
                  (void*)&ksum, (void*)&kv, (void*)&out};
  hipError_t err = hipLaunchCooperativeKernel((void*)fused_tail, dim3(NCH_),
                                              dim3(256), args, 0, stream);
  if (err != hipSuccess) {
    // Deterministic fallback: round-7 proven path.
    chunksum_kernel<<<NCH_, 256, 0, stream>>>(k, v, kc, ksum, kv);
    constexpr int SCAN_TOTAL = BH_ * (DK_ * DV_ + DK_);
    scan_kernel<<<(SCAN_TOTAL + 255) / 256, 256, 0, stream>>>(ksum, kv);
    out_mfma_kernel<<<NCH_, 256, 0, stream>>>(q, k, v, qc, kc, ksum, kv, out);
  }
}

// Round 10
// 69.010 us; speedup vs baseline: 2.7761x; 2.7761x over previous
//
#include <hip/hip_runtime.h>
#include <cmath>

constexpr int B_ = 2, H_ = 8, N_ = 2048, DK_ = 64, DV_ = 64;
constexpr int BH_ = B_ * H_;      // 16
constexpr int C_ = 64;            // chunk size
constexpr int NC_ = N_ / C_;      // 32 chunks per (b,h)
constexpr int NCH_ = BH_ * NC_;   // 512 chunks total
constexpr int SCAN_BLOCKS = (BH_ * ((DK_ * DV_) / 4 + DK_ / 4)) / 256; // 65

using f32x16 = __attribute__((ext_vector_type(16))) float;
using bf16x8 = __attribute__((ext_vector_type(8))) __bf16;

__device__ inline unsigned short bfr(float x) {
  unsigned u = __float_as_uint(x);
  return (unsigned short)((u + 0x7FFFu + ((u >> 16) & 1u)) >> 16);
}
__device__ inline unsigned pk2(float lo, float hi) {
  return (unsigned)bfr(lo) | ((unsigned)bfr(hi) << 16);
}
// swizzled ushort index into a [64][64] bf16 tile (row stride 128B)
__device__ inline int swi(int row, int a) {
  return (row * 128 + (((a * 2) ^ ((row & 7) << 4)))) >> 1;
}

// ---------------------------------------------------------------------------
// Kernel 1: per-chunk sums. kc computed INLINE from omask[:,0] (64 scattered
// loads -> LDS) so this kernel has no dependency on coef and can run first.
// ---------------------------------------------------------------------------
__global__ __launch_bounds__(256) void chunksum_kernel(const float* __restrict__ kg,
                                                       const float* __restrict__ vg,
                                                       const float* __restrict__ om,
                                                       float* __restrict__ ksum,
                                                       float* __restrict__ kvsum) {
  __shared__ float kb[C_][DK_];
  __shared__ float vs[C_][DV_];
  __shared__ float smkc[C_];
  int chunk = blockIdx.x;
  int bh = chunk / NC_, ci = chunk - bh * NC_;
  int r0 = ci * C_;
  int rowb = bh * N_ + r0;
  size_t gbase = (size_t)rowb * DK_;
  int t = threadIdx.x;
  if (t < 64) smkc[t] = 1.0f / om[(size_t)(rowb + t) * N_];
  __syncthreads();
#pragma unroll
  for (int p = 0; p < 4; ++p) {
    int f = t + p * 256;
    int row = f >> 4, col = (f & 15) * 4;
    float sc = smkc[row];
    float4 k4 = *(const float4*)(kg + gbase + (size_t)f * 4);
    k4.x *= sc; k4.y *= sc; k4.z *= sc; k4.w *= sc;
    *(float4*)&kb[row][col] = k4;
    *(float4*)&vs[row][col] = *(const float4*)(vg + gbase + (size_t)f * 4);
  }
  __syncthreads();
  int dk0 = (t & 15) * 4, dv0 = (t >> 4) * 4;
  float acc[4][4] = {};
  float ks[4] = {};
  for (int r = 0; r < C_; ++r) {
    float4 k4 = *(const float4*)&kb[r][dk0];
    float4 v4 = *(const float4*)&vs[r][dv0];
    float ka[4] = {k4.x, k4.y, k4.z, k4.w};
    float va[4] = {v4.x, v4.y, v4.z, v4.w};
#pragma unroll
    for (int i = 0; i < 4; ++i) {
      ks[i] += ka[i];
#pragma unroll
      for (int j = 0; j < 4; ++j) acc[i][j] += ka[i] * va[j];
    }
  }
  float* kvc = kvsum + (size_t)chunk * (DK_ * DV_);
#pragma unroll
  for (int i = 0; i < 4; ++i)
    *(float4*)(kvc + (size_t)(dk0 + i) * DV_ + dv0) =
        make_float4(acc[i][0], acc[i][1], acc[i][2], acc[i][3]);
  if (t < 16) {
#pragma unroll
    for (int i = 0; i < 4; ++i) ksum[(size_t)chunk * DK_ + dk0 + i] = ks[i];
  }
}

// ---------------------------------------------------------------------------
// Kernel 2: blocks 0..64  -> exclusive prefix scan (in-place, float4,
//                            prefetch-8: 32 dependent loads -> 4 batches)
//           blocks 65..   -> coef (round-1 proven shape, row-shifted).
// Scan blocks are FIRST so they run concurrently with the 45us omask stream.
// ---------------------------------------------------------------------------
__global__ __launch_bounds__(256) void coef_scan_kernel(const float* __restrict__ om,
                                                        float* __restrict__ qc,
                                                        float* __restrict__ kc,
                                                        float* __restrict__ ksum,
                                                        float* __restrict__ kvsum) {
  int t = threadIdx.x;
  if (blockIdx.x < SCAN_BLOCKS) {
    constexpr int PER4 = (DK_ * DV_) / 4 + DK_ / 4;   // 1040 per bh
    int idx = blockIdx.x * 256 + t;                   // < 16640 always
    int bh = idx / PER4, e = idx - bh * PER4;
    float4* p;
    size_t stride;
    if (e < (DK_ * DV_) / 4) {
      p = (float4*)(kvsum + (size_t)bh * NC_ * (DK_ * DV_)) + e;
      stride = (DK_ * DV_) / 4;
    } else {
      p = (float4*)(ksum + (size_t)bh * NC_ * DK_) + (e - (DK_ * DV_) / 4);
      stride = DK_ / 4;
    }
    float4 run = make_float4(0.f, 0.f, 0.f, 0.f);
    float4 buf[8];
    for (int b = 0; b < NC_ / 8; ++b) {
#pragma unroll
      for (int u = 0; u < 8; ++u) buf[u] = p[(size_t)(b * 8 + u) * stride];
#pragma unroll
      for (int u = 0; u < 8; ++u) {
        p[(size_t)(b * 8 + u) * stride] = run;
        run.x += buf[u].x; run.y += buf[u].y;
        run.z += buf[u].z; run.w += buf[u].w;
      }
    }
  } else {
    int row = (blockIdx.x - SCAN_BLOCKS) * 4 + (t >> 6);
    int lane = t & 63;
    const float* r = om + (size_t)row * N_;
    float s = 0.f;
#pragma unroll
    for (int kk = 0; kk < N_ / 256; ++kk) {
      float4 v4 = *(const float4*)(r + kk * 256 + lane * 4);
      s += (v4.x + v4.y) + (v4.z + v4.w);
    }
#pragma unroll
    for (int off = 32; off > 0; off >>= 1) s += __shfl_xor(s, off, 64);
    if (lane == 0) {
      float o0 = r[0];
      qc[row] = o0 / sqrtf(s);
      kc[row] = 1.0f / o0;
    }
  }
}

// ---------------------------------------------------------------------------
// Kernel 3 (round-7 proven, unchanged): MFMA numerator + f32 P.
// ---------------------------------------------------------------------------
__global__ __launch_bounds__(256) void out_mfma_kernel(
    const float* __restrict__ qg, const float* __restrict__ kg,
    const float* __restrict__ vg, const float* __restrict__ qc,
    const float* __restrict__ kc, const float* __restrict__ ksum,
    const float* __restrict__ kvsum, float* __restrict__ outg) {
  __shared__ unsigned short qb[64 * 64];
  __shared__ unsigned short kb[64 * 64];
  __shared__ unsigned short sS[64 * 64];
  __shared__ unsigned short vT[64 * 64];
  __shared__ unsigned short dT[64 * 64];
  __shared__ float Tc[2][64][68];
  __shared__ float Tl[64];
  __shared__ float Pf[64];

  const int chunk = blockIdx.x;
  const int bh = chunk >> 5, ci = chunk & 31;
  const int r0 = ci * C_;
  const int rowb = bh * N_ + r0;
  const size_t gbase = (size_t)rowb * DK_;
  const int t = threadIdx.x;
  const int i = t >> 2, a0 = (t & 3) * 16;

  float xq[16];
  {
    float qcv = qc[rowb + i];
    float kcv = kc[rowb + i];
    float xk[16], xv[16], xd[16];
    {
      const float* qp = qg + gbase + (size_t)i * 64 + a0;
      const float* kp = kg + gbase + (size_t)i * 64 + a0;
      const float* vp = vg + gbase + (size_t)i * 64 + a0;
      const float* dp = kvsum + (size_t)chunk * (DK_ * DV_) + (size_t)i * 64 + a0;
#pragma unroll
      for (int u = 0; u < 4; ++u) {
        *(float4*)&xq[u * 4] = *(const float4*)(qp + u * 4);
        *(float4*)&xk[u * 4] = *(const float4*)(kp + u * 4);
        *(float4*)&xv[u * 4] = *(const float4*)(vp + u * 4);
        *(float4*)&xd[u * 4] = *(const float4*)(dp + u * 4);
      }
    }
#pragma unroll
    for (int u = 0; u < 16; ++u) { xq[u] *= qcv; xk[u] *= kcv; }
#pragma unroll
    for (int u4 = 0; u4 < 4; ++u4)
      *(float4*)&Tc[0][i][a0 + u4 * 4] = *(const float4*)&xk[u4 * 4];
    unsigned* qbu = (unsigned*)qb;
    unsigned* kbu = (unsigned*)kb;
#pragma unroll
    for (int u = 0; u < 8; ++u) {
      int a = a0 + 2 * u;
      int bi = (i * 128 + (((a * 2) ^ ((i & 7) << 4)))) >> 2;
      qbu[bi] = pk2(xq[2 * u], xq[2 * u + 1]);
      kbu[bi] = pk2(xk[2 * u], xk[2 * u + 1]);
    }
#pragma unroll
    for (int u = 0; u < 16; ++u) {
      int c = a0 + u;
      vT[swi(c, i)] = bfr(xv[u]);
      dT[swi(c, i)] = bfr(xd[u]);
    }
    if (t < 64) Tl[t] = ksum[(size_t)chunk * DK_ + t];
  }
  __syncthreads();
  {
    int p = 0;
#pragma unroll
    for (int step = 1; step < 64; step <<= 1) {
      float4 cur[4], prv[4];
#pragma unroll
      for (int u4 = 0; u4 < 4; ++u4) {
        cur[u4] = *(const float4*)&Tc[p][i][a0 + u4 * 4];
        if (i >= step)
          prv[u4] = *(const float4*)&Tc[p][i - step][a0 + u4 * 4];
        else
          prv[u4] = make_float4(0.f, 0.f, 0.f, 0.f);
      }
#pragma unroll
      for (int u4 = 0; u4 < 4; ++u4) {
        float4 w = make_float4(cur[u4].x + prv[u4].x, cur[u4].y + prv[u4].y,
                               cur[u4].z + prv[u4].z, cur[u4].w + prv[u4].w);
        *(float4*)&Tc[p ^ 1][i][a0 + u4 * 4] = w;
      }
      __syncthreads();
      p ^= 1;
    }
  }
  {
    float part = 0.f;
#pragma unroll
    for (int u = 0; u < 16; ++u)
      part += xq[u] * (Tl[a0 + u] + Tc[0][i][a0 + u]);
    part += __shfl_xor(part, 1, 64);
    part += __shfl_xor(part, 2, 64);
    if ((t & 3) == 0) Pf[i] = 1.0f / fmaxf(fabsf(part), 1.0f);
  }
  const int lane = t & 63, w = t >> 6;
  const int wr = w >> 1, wc = w & 1;
  const int half = lane >> 5, col = lane & 31;
  const int arow = 32 * wr + col;
  const int bcol = 32 * wc + col;
  f32x16 accS;
#pragma unroll
  for (int r = 0; r < 16; ++r) accS[r] = 0.f;
#pragma unroll
  for (int kk = 0; kk < 4; ++kk) {
    int aa = kk * 16 + half * 8;
    bf16x8 af = *(const bf16x8*)&qb[swi(arow, aa)];
    bf16x8 bf = *(const bf16x8*)&kb[swi(bcol, aa)];
    accS = __builtin_amdgcn_mfma_f32_32x32x16_bf16(af, bf, accS, 0, 0, 0);
  }
#pragma unroll
  for (int r = 0; r < 16; ++r) {
    int iloc = (r & 3) + 8 * (r >> 2) + 4 * half;
    int ii = 32 * wr + iloc;
    int jj = 32 * wc + col;
    float m = (jj <= ii) ? accS[r] : 0.f;
    sS[swi(ii, jj)] = bfr(m);
  }
  __syncthreads();
  f32x16 acc;
#pragma unroll
  for (int r = 0; r < 16; ++r) acc[r] = 0.f;
#pragma unroll
  for (int kk = 0; kk < 4; ++kk) {
    int j0 = kk * 16 + half * 8;
    bf16x8 af = *(const bf16x8*)&sS[swi(arow, j0)];
    bf16x8 bf = *(const bf16x8*)&vT[swi(bcol, j0)];
    acc = __builtin_amdgcn_mfma_f32_32x32x16_bf16(af, bf, acc, 0, 0, 0);
  }
#pragma unroll
  for (int kk = 0; kk < 4; ++kk) {
    int aa = kk * 16 + half * 8;
    bf16x8 af = *(const bf16x8*)&qb[swi(arow, aa)];
    bf16x8 bf = *(const bf16x8*)&dT[swi(bcol, aa)];
    acc = __builtin_amdgcn_mfma_f32_32x32x16_bf16(af, bf, acc, 0, 0, 0);
  }
  float* ob = outg + (size_t)rowb * DV_;
#pragma unroll
  for (int r = 0; r < 16; ++r) {
    int iloc = (r & 3) + 8 * (r >> 2) + 4 * half;
    int ii = 32 * wr + iloc;
    int cc = 32 * wc + col;
    ob[(size_t)ii * DV_ + cc] = acc[r] * Pf[ii];
  }
}

// ---------------------------------------------------------------------------
extern "C" void kernel_launch(void* const* d_in, const int* in_sizes, int n_in,
                              void* d_out, int out_size, void* d_ws, size_t ws_size,
                              hipStream_t stream) {
  const float* q = (const float*)d_in[0];
  const float* k = (const float*)d_in[1];
  const float* v = (const float*)d_in[2];
  const float* om = (const float*)d_in[3];
  float* out = (float*)d_out;

  float* ws = (float*)d_ws;
  float* qc = ws;                          // BH_*N_       = 32768
  float* kc = qc + BH_ * N_;               // BH_*N_       = 32768
  float* ksum = kc + BH_ * N_;             // NCH_*DK_     = 32768
  float* kv = ksum + (size_t)NCH_ * DK_;   // NCH_*DK_*DV_ = 2,097,152

  chunksum_kernel<<<NCH_, 256, 0, stream>>>(k, v, om, ksum, kv);
  coef_scan_kernel<<<SCAN_BLOCKS + BH_ * N_ / 4, 256, 0, stream>>>(om, qc, kc,
                                                                   ksum, kv);
  out_mfma_kernel<<<NCH_, 256, 0, stream>>>(q, k, v, qc, kc, ksum, kv, out);
}